// Round 1
// baseline (1444.609 us; speedup 1.0000x reference)
//
#include <hip/hip_runtime.h>

typedef __attribute__((ext_vector_type(8))) short short8;
typedef __attribute__((ext_vector_type(4))) short short4_t;
typedef __attribute__((ext_vector_type(4))) float f32x4;

#define MFMA(a,b,c) __builtin_amdgcn_mfma_f32_16x16x32_bf16((a),(b),(c),0,0,0)

__device__ __forceinline__ unsigned short f2bf(float f){
  unsigned u = __builtin_bit_cast(unsigned, f);
  u += 0x7FFFu + ((u >> 16) & 1u);
  return (unsigned short)(u >> 16);
}
__device__ __forceinline__ float bf2f(unsigned short h){
  unsigned u = ((unsigned)h) << 16;
  return __builtin_bit_cast(float, u);
}
__device__ __forceinline__ f32x4 vmax4(f32x4 a, f32x4 b){
  f32x4 r;
  r[0]=fmaxf(a[0],b[0]); r[1]=fmaxf(a[1],b[1]);
  r[2]=fmaxf(a[2],b[2]); r[3]=fmaxf(a[3],b[3]);
  return r;
}

// ws layout (shorts):
//   0     : wq_hi 27648 bf16   (qkv_w hi, B-frag layout [kt3][nt18][lane64][j8])
//   27648 : wq_lo 27648
//   55296 : wp_hi  9216        (proj_w,  [kt3][nt6][lane64][j8])
//   64512 : wp_lo  9216
//   73728 : biasf 12288 f32    ([h3][mt4][nt4][lane64][r4], -1e30 mask for n>=49)
// total 196608 bytes

__global__ void prep_kernel(const float* __restrict__ qkv_w,
                            const float* __restrict__ proj_w,
                            const float* __restrict__ bias_table,
                            const int* __restrict__ rel_index,
                            unsigned short* __restrict__ ws){
  int id = blockIdx.x * 256 + threadIdx.x;
  if (id < 27648){
    int j = id & 7, lane = (id >> 3) & 63, nt = (id >> 9) % 18, kt = id / 9216;
    int n = nt*16 + (lane & 15);
    int k = kt*32 + ((lane >> 4) << 3) + j;
    float v = qkv_w[k*288 + n];
    unsigned short hi = f2bf(v);
    ws[id] = hi;
    ws[27648 + id] = f2bf(v - bf2f(hi));
  } else if (id < 36864){
    int id2 = id - 27648;
    int j = id2 & 7, lane = (id2 >> 3) & 63, nt = (id2 >> 9) % 6, kt = id2 / 3072;
    int n = nt*16 + (lane & 15);
    int k = kt*32 + ((lane >> 4) << 3) + j;
    float v = proj_w[k*96 + n];
    unsigned short hi = f2bf(v);
    ws[55296 + id2] = hi;
    ws[64512 + id2] = f2bf(v - bf2f(hi));
  } else if (id < 49152){
    int id3 = id - 36864;
    int r = id3 & 3, lane = (id3 >> 2) & 63, nt = (id3 >> 8) & 3, mt = (id3 >> 10) & 3, h = id3 >> 12;
    int m = mt*16 + ((lane >> 4) << 2) + r;
    int n = nt*16 + (lane & 15);
    float v;
    if (n >= 49) v = -1e30f;            // pad kv cols -> softmax weight 0
    else if (m >= 49) v = 0.0f;          // pad q rows: finite garbage, discarded
    else v = bias_table[rel_index[m*49 + n]*3 + h];
    ((float*)(ws + 73728))[id3] = v;
  }
}

// One window per block. 256 threads = 4 waves.
// LDS (157696 B): xs_hi/lo [64][104]bf16 | qk_hi/lo [64][296]bf16 | ps_hi/lo [3][64][72]bf16
// os fp32 [64][104] overlays xs (xs dead after qkv stage).
__global__ __launch_bounds__(256, 1)
void wattn_kernel(const float* __restrict__ x,
                  const float* __restrict__ qkv_b,
                  const float* __restrict__ proj_b,
                  const unsigned short* __restrict__ ws,
                  float* __restrict__ out){
  const unsigned short* wq_hi = ws;
  const unsigned short* wq_lo = ws + 27648;
  const unsigned short* wp_hi = ws + 55296;
  const unsigned short* wp_lo = ws + 64512;
  const float* biasf = (const float*)(ws + 73728);

  extern __shared__ char smem[];
  unsigned short* xs_hi = (unsigned short*)smem;             // [64][104]
  unsigned short* xs_lo = xs_hi + 6656;
  unsigned short* qk_hi = (unsigned short*)(smem + 26624);   // [64][296]
  unsigned short* qk_lo = qk_hi + 18944;
  unsigned short* ps_hi = (unsigned short*)(smem + 102400);  // [3][64][72]
  unsigned short* ps_lo = ps_hi + 13824;
  float* os = (float*)smem;                                   // [64][104] overlay

  const int b = blockIdx.x;
  const int tid = (int)threadIdx.x;
  const int w = tid >> 6;
  const int lane = tid & 63;
  const int g = lane >> 4;
  const int c = lane & 15;

  // ---- stage 0: load x -> split bf16 LDS, zero-pad rows 49..63 ----
  {
    const float* xw = x + (size_t)b * 4704;
    for (int i = tid; i < 1176; i += 256){
      f32x4 v = *(const f32x4*)(xw + i*4);
      int row = i / 24, col = (i % 24) * 4;
      short4_t h4, l4;
      #pragma unroll
      for (int j = 0; j < 4; ++j){
        unsigned short hh = f2bf(v[j]);
        h4[j] = (short)hh;
        l4[j] = (short)f2bf(v[j] - bf2f(hh));
      }
      *(short4_t*)(xs_hi + row*104 + col) = h4;
      *(short4_t*)(xs_lo + row*104 + col) = l4;
    }
    for (int i = tid; i < 780; i += 256){   // 15 rows * 52 dword-pairs
      int row = 49 + i/52, col = (i%52)*2;
      *(unsigned*)(xs_hi + row*104 + col) = 0u;
      *(unsigned*)(xs_lo + row*104 + col) = 0u;
    }
  }
  __syncthreads();

  // ---- stage 1: qkv = x @ Wqkv + b (q pre-scaled); n-tiles split across waves ----
  {
    f32x4 acc[5][4];
    #pragma unroll
    for (int s = 0; s < 5; ++s)
      #pragma unroll
      for (int mt = 0; mt < 4; ++mt){ f32x4 z = {0.f,0.f,0.f,0.f}; acc[s][mt] = z; }
    #pragma unroll
    for (int kt = 0; kt < 3; ++kt){
      short8 ahi[4], alo[4];
      #pragma unroll
      for (int mt = 0; mt < 4; ++mt){
        int off = (mt*16 + c)*104 + kt*32 + g*8;
        ahi[mt] = *(const short8*)(xs_hi + off);
        alo[mt] = *(const short8*)(xs_lo + off);
      }
      short8 bhi[5], blo[5];
      #pragma unroll
      for (int s = 0; s < 5; ++s){
        if (s == 4 && w >= 2) continue;
        int nt = w + s*4;
        int boff = ((kt*18 + nt)*64 + lane)*8;
        bhi[s] = *(const short8*)(wq_hi + boff);
        blo[s] = *(const short8*)(wq_lo + boff);
      }
      #pragma unroll
      for (int s = 0; s < 5; ++s){
        if (s == 4 && w >= 2) continue;
        #pragma unroll
        for (int mt = 0; mt < 4; ++mt){
          acc[s][mt] = MFMA(ahi[mt], bhi[s], acc[s][mt]);
          acc[s][mt] = MFMA(ahi[mt], blo[s], acc[s][mt]);
          acc[s][mt] = MFMA(alo[mt], bhi[s], acc[s][mt]);
        }
      }
    }
    #pragma unroll
    for (int s = 0; s < 5; ++s){
      if (s == 4 && w >= 2) continue;
      int nt = w + s*4;
      int n = nt*16 + c;
      float bv = qkv_b[n];
      float sc = (nt < 6) ? 0.17677669529663687f : 1.0f;  // q *= hd^-0.5
      #pragma unroll
      for (int mt = 0; mt < 4; ++mt)
        #pragma unroll
        for (int r = 0; r < 4; ++r){
          float v2 = (acc[s][mt][r] + bv) * sc;
          unsigned short hi = f2bf(v2);
          int row = mt*16 + g*4 + r;
          qk_hi[row*296 + n] = hi;
          qk_lo[row*296 + n] = f2bf(v2 - bf2f(hi));
        }
    }
  }
  __syncthreads();

  // ---- stage 2: attention. 12 (head,mtile) units; wave w owns units 3w..3w+2 ----
  {
    int hprev = -1;
    short8 khi[4], klo[4], vhi[2][2], vlo[2][2];
    #pragma unroll
    for (int p = 0; p < 3; ++p){
      const int u3 = w*3 + p;
      const int h = u3 >> 2, mt = u3 & 3;
      if (h != hprev){
        hprev = h;
        #pragma unroll
        for (int nt = 0; nt < 4; ++nt){
          int off = (nt*16 + c)*296 + 96 + h*32 + g*8;   // K^T B-frag: col=kv tok
          khi[nt] = *(const short8*)(qk_hi + off);
          klo[nt] = *(const short8*)(qk_lo + off);
        }
        #pragma unroll
        for (int ks = 0; ks < 2; ++ks)
          #pragma unroll
          for (int u = 0; u < 2; ++u){
            short8 th, tl;
            #pragma unroll
            for (int j = 0; j < 8; ++j){
              int off = (ks*32 + g*8 + j)*296 + 192 + h*32 + u*16 + c;
              th[j] = (short)qk_hi[off];
              tl[j] = (short)qk_lo[off];
            }
            vhi[ks][u] = th; vlo[ks][u] = tl;
          }
      }
      int qoff = (mt*16 + c)*296 + h*32 + g*8;
      const short8 qhi = *(const short8*)(qk_hi + qoff);
      const short8 qlo = *(const short8*)(qk_lo + qoff);
      f32x4 bfr[4];
      #pragma unroll
      for (int nt = 0; nt < 4; ++nt)
        bfr[nt] = *(const f32x4*)(biasf + (((h*4+mt)*4+nt)*64 + lane)*4);
      f32x4 sv[4];
      #pragma unroll
      for (int nt = 0; nt < 4; ++nt){
        f32x4 a = {0.f,0.f,0.f,0.f};
        a = MFMA(qhi, khi[nt], a);
        a = MFMA(qhi, klo[nt], a);
        a = MFMA(qlo, khi[nt], a);
        sv[nt] = a + bfr[nt];
      }
      // softmax over 64 kv cols (rows live in 16-lane groups)
      f32x4 mx = vmax4(vmax4(sv[0],sv[1]), vmax4(sv[2],sv[3]));
      #pragma unroll
      for (int off = 1; off <= 8; off <<= 1){
        #pragma unroll
        for (int i2 = 0; i2 < 4; ++i2) mx[i2] = fmaxf(mx[i2], __shfl_xor(mx[i2], off));
      }
      #pragma unroll
      for (int nt = 0; nt < 4; ++nt)
        #pragma unroll
        for (int r = 0; r < 4; ++r)
          sv[nt][r] = exp2f((sv[nt][r] - mx[r]) * 1.4426950408889634f);
      f32x4 sm = sv[0] + sv[1] + sv[2] + sv[3];
      #pragma unroll
      for (int off = 1; off <= 8; off <<= 1){
        #pragma unroll
        for (int i2 = 0; i2 < 4; ++i2) sm[i2] += __shfl_xor(sm[i2], off);
      }
      f32x4 rs;
      #pragma unroll
      for (int r = 0; r < 4; ++r) rs[r] = __builtin_amdgcn_rcpf(sm[r]);
      // store P (unnormalized) split
      #pragma unroll
      for (int nt = 0; nt < 4; ++nt)
        #pragma unroll
        for (int r = 0; r < 4; ++r){
          float pv2 = sv[nt][r];
          unsigned short hi2 = f2bf(pv2);
          int off2 = h*4608 + (mt*16 + g*4 + r)*72 + nt*16 + c;
          ps_hi[off2] = hi2;
          ps_lo[off2] = f2bf(pv2 - bf2f(hi2));
        }
      // P A-frags (same wave wrote them; in-wave DS ordering suffices)
      short8 phi[2], plo[2];
      #pragma unroll
      for (int ks = 0; ks < 2; ++ks){
        int off3 = h*4608 + (mt*16 + c)*72 + ks*32 + g*8;
        phi[ks] = *(const short8*)(ps_hi + off3);
        plo[ks] = *(const short8*)(ps_lo + off3);
      }
      // O = (P @ V) * 1/rowsum
      #pragma unroll
      for (int u = 0; u < 2; ++u){
        f32x4 o = {0.f,0.f,0.f,0.f};
        #pragma unroll
        for (int ks = 0; ks < 2; ++ks){
          o = MFMA(phi[ks], vhi[ks][u], o);
          o = MFMA(phi[ks], vlo[ks][u], o);
          o = MFMA(plo[ks], vhi[ks][u], o);
        }
        #pragma unroll
        for (int r = 0; r < 4; ++r)
          os[(mt*16 + g*4 + r)*104 + h*32 + u*16 + c] = o[r] * rs[r];
      }
    }
  }
  __syncthreads();

  // ---- stage 3: out = O @ Wproj + b ----
  {
    f32x4 pacc[2][4];
    #pragma unroll
    for (int s2 = 0; s2 < 2; ++s2)
      #pragma unroll
      for (int mt = 0; mt < 4; ++mt){ f32x4 z = {0.f,0.f,0.f,0.f}; pacc[s2][mt] = z; }
    #pragma unroll
    for (int kt = 0; kt < 3; ++kt){
      short8 ahi[4], alo[4];
      #pragma unroll
      for (int mt = 0; mt < 4; ++mt){
        int off = (mt*16 + c)*104 + kt*32 + g*8;
        f32x4 w0 = *(const f32x4*)(os + off);
        f32x4 w1 = *(const f32x4*)(os + off + 4);
        short8 th, tl;
        #pragma unroll
        for (int j = 0; j < 4; ++j){
          unsigned short hh = f2bf(w0[j]);
          th[j] = (short)hh; tl[j] = (short)f2bf(w0[j] - bf2f(hh));
          unsigned short hh2 = f2bf(w1[j]);
          th[j+4] = (short)hh2; tl[j+4] = (short)f2bf(w1[j] - bf2f(hh2));
        }
        ahi[mt] = th; alo[mt] = tl;
      }
      short8 bhi[2], blo[2];
      #pragma unroll
      for (int s2 = 0; s2 < 2; ++s2){
        if (s2 == 1 && w >= 2) continue;
        int nt = w + s2*4;
        int boff = ((kt*6 + nt)*64 + lane)*8;
        bhi[s2] = *(const short8*)(wp_hi + boff);
        blo[s2] = *(const short8*)(wp_lo + boff);
      }
      #pragma unroll
      for (int s2 = 0; s2 < 2; ++s2){
        if (s2 == 1 && w >= 2) continue;
        #pragma unroll
        for (int mt = 0; mt < 4; ++mt){
          pacc[s2][mt] = MFMA(ahi[mt], bhi[s2], pacc[s2][mt]);
          pacc[s2][mt] = MFMA(ahi[mt], blo[s2], pacc[s2][mt]);
          pacc[s2][mt] = MFMA(alo[mt], bhi[s2], pacc[s2][mt]);
        }
      }
    }
    #pragma unroll
    for (int s2 = 0; s2 < 2; ++s2){
      if (s2 == 1 && w >= 2) continue;
      int nt = w + s2*4;
      int n = nt*16 + c;
      float pb = proj_b[n];
      #pragma unroll
      for (int mt = 0; mt < 4; ++mt)
        #pragma unroll
        for (int r = 0; r < 4; ++r){
          int row = mt*16 + g*4 + r;
          if (row < 49)
            out[((size_t)b*49 + row)*96 + n] = pacc[s2][mt][r] + pb;
        }
    }
  }
}

extern "C" void kernel_launch(void* const* d_in, const int* in_sizes, int n_in,
                              void* d_out, int out_size, void* d_ws, size_t ws_size,
                              hipStream_t stream){
  const float* x          = (const float*)d_in[0];
  // d_in[1] = q_global (unused by forward)
  const float* qkv_w      = (const float*)d_in[2];
  const float* qkv_b      = (const float*)d_in[3];
  const float* proj_w     = (const float*)d_in[4];
  const float* proj_b     = (const float*)d_in[5];
  const float* bias_table = (const float*)d_in[6];
  const int*   rel_index  = (const int*)d_in[7];
  float* out = (float*)d_out;
  const int nwin = in_sizes[0] / 4704;   // 49*96

  prep_kernel<<<192, 256, 0, stream>>>(qkv_w, proj_w, bias_table, rel_index,
                                       (unsigned short*)d_ws);

  hipFuncSetAttribute(reinterpret_cast<const void*>(wattn_kernel),
                      hipFuncAttributeMaxDynamicSharedMemorySize, 157696);
  wattn_kernel<<<nwin, 256, 157696, stream>>>(x, qkv_b, proj_b,
                                              (const unsigned short*)d_ws, out);
}

// Round 3
// 854.284 us; speedup vs baseline: 1.6910x; 1.6910x over previous
//
#include <hip/hip_runtime.h>

typedef __attribute__((ext_vector_type(8))) short short8;
typedef __attribute__((ext_vector_type(4))) short short4_t;
typedef __attribute__((ext_vector_type(4))) float f32x4;

#define MFMA(a,b,c) __builtin_amdgcn_mfma_f32_16x16x32_bf16((a),(b),(c),0,0,0)

__device__ __forceinline__ unsigned short f2bf(float f){
  unsigned u = __builtin_bit_cast(unsigned, f);
  u += 0x7FFFu + ((u >> 16) & 1u);
  return (unsigned short)(u >> 16);
}
__device__ __forceinline__ f32x4 vmax4(f32x4 a, f32x4 b){
  f32x4 r;
  r[0]=fmaxf(a[0],b[0]); r[1]=fmaxf(a[1],b[1]);
  r[2]=fmaxf(a[2],b[2]); r[3]=fmaxf(a[3],b[3]);
  return r;
}

// ws layout (shorts):
//   0     : wq 27648 bf16  (qkv_w, B-frag layout [kt3][nt18][lane64][j8])
//   27648 : wp  9216 bf16  (proj_w, [kt3][nt6][lane64][j8])
//   36864 : biasf 12288 f32 ([h3][mt4][nt4][lane64][r4], -1e30 mask for n>=49)
// total 122880 bytes

__global__ void prep_kernel(const float* __restrict__ qkv_w,
                            const float* __restrict__ proj_w,
                            const float* __restrict__ bias_table,
                            const int* __restrict__ rel_index,
                            unsigned short* __restrict__ ws){
  int id = blockIdx.x * 256 + threadIdx.x;
  if (id < 27648){
    int j = id & 7, lane = (id >> 3) & 63, nt = (id >> 9) % 18, kt = id / 9216;
    int n = nt*16 + (lane & 15);
    int k = kt*32 + ((lane >> 4) << 3) + j;
    ws[id] = f2bf(qkv_w[k*288 + n]);
  } else if (id < 36864){
    int id2 = id - 27648;
    int j = id2 & 7, lane = (id2 >> 3) & 63, nt = (id2 >> 9) % 6, kt = id2 / 3072;
    int n = nt*16 + (lane & 15);
    int k = kt*32 + ((lane >> 4) << 3) + j;
    ws[27648 + id2] = f2bf(proj_w[k*96 + n]);
  } else if (id < 49152){
    int id3 = id - 36864;
    int r = id3 & 3, lane = (id3 >> 2) & 63, nt = (id3 >> 8) & 3, mt = (id3 >> 10) & 3, h = id3 >> 12;
    int m = mt*16 + ((lane >> 4) << 2) + r;
    int n = nt*16 + (lane & 15);
    float v;
    if (n >= 49) v = -1e30f;            // pad kv cols -> softmax weight 0
    else if (m >= 49) v = 0.0f;          // pad q rows: finite garbage, discarded
    else v = bias_table[rel_index[m*49 + n]*3 + h];
    ((float*)(ws + 36864))[id3] = v;
  }
}

// One window per block, 4 waves. All bf16-single MFMA, fp32 accumulate.
// LDS (61440 B, shorts):
//   xs [64][128] @0      (x, XOR-swizzled; per-wave [16][128] slice reused as O scratch)
//   qs [64][128] @8192   (Q, swizzled; per-wave slice reused as P scratch)
//   ks [64][128] @16384  (K, swizzled)
//   vT [96][64]  @24576  (V transposed [d][kv], swizzled)
// Swizzle: addr = row*STRIDE + ((col8 ^ (row&7))<<3) + (col&7)
__global__ __launch_bounds__(256, 2)
void wattn_kernel(const float* __restrict__ x,
                  const float* __restrict__ qkv_b,
                  const float* __restrict__ proj_b,
                  const unsigned short* __restrict__ ws,
                  float* __restrict__ out){
  const unsigned short* wq = ws;
  const unsigned short* wp = ws + 27648;
  const float* biasf = (const float*)(ws + 36864);

  extern __shared__ char smem[];
  unsigned short* xs = (unsigned short*)smem;   // [64][128]
  unsigned short* qs = xs + 8192;               // [64][128]
  unsigned short* ks = xs + 16384;              // [64][128]
  unsigned short* vT = xs + 24576;              // [96][64]

  const int b = blockIdx.x;
  const int tid = (int)threadIdx.x;
  const int w = tid >> 6;
  const int lane = tid & 63;
  const int g = lane >> 4;
  const int c = lane & 15;
  const int c7 = c & 7;

  // ---- stage 0: x -> bf16 LDS (swizzled), zero-pad rows 49..63 ----
  {
    const float* xw = x + (size_t)b * 4704;
    for (int i = tid; i < 1176; i += 256){
      f32x4 v = *(const f32x4*)(xw + i*4);
      int row = i / 24, q4 = i % 24;             // col = q4*4
      short4_t h4;
      #pragma unroll
      for (int j = 0; j < 4; ++j) h4[j] = (short)f2bf(v[j]);
      int addr = row*128 + (((q4>>1) ^ (row&7))<<3) + ((q4&1)<<2);
      *(short4_t*)(xs + addr) = h4;
    }
    for (int i = tid; i < 960; i += 256)         // rows 49..63 full-row zero
      ((unsigned*)xs)[49*64 + i] = 0u;
  }
  __syncthreads();

  // ---- stage 1: qkv = x @ Wqkv + b; n-tiles split across waves ----
  {
    f32x4 acc[5][4];
    #pragma unroll
    for (int s = 0; s < 5; ++s)
      #pragma unroll
      for (int mt = 0; mt < 4; ++mt){ f32x4 z = {0.f,0.f,0.f,0.f}; acc[s][mt] = z; }
    #pragma unroll
    for (int kt = 0; kt < 3; ++kt){
      short8 af[4];
      #pragma unroll
      for (int mt = 0; mt < 4; ++mt){
        int row = mt*16 + c;
        af[mt] = *(const short8*)(xs + row*128 + (((kt*4+g) ^ c7)<<3));
      }
      short8 bf[5];
      #pragma unroll
      for (int s = 0; s < 5; ++s){
        if (s == 4 && w >= 2) continue;
        int nt = s*4 + w;
        bf[s] = *(const short8*)(wq + ((kt*18 + nt)*64 + lane)*8);
      }
      #pragma unroll
      for (int s = 0; s < 5; ++s){
        if (s == 4 && w >= 2) continue;
        #pragma unroll
        for (int mt = 0; mt < 4; ++mt)
          acc[s][mt] = MFMA(af[mt], bf[s], acc[s][mt]);
      }
    }
    // epilogue: route to Q / K / V^T
    #pragma unroll
    for (int s = 0; s < 5; ++s){
      if (s == 4 && w >= 2) continue;
      int nt = s*4 + w;
      float bv = qkv_b[nt*16 + c];
      if (nt < 6){                               // Q (pre-scaled)
        #pragma unroll
        for (int mt = 0; mt < 4; ++mt)
          #pragma unroll
          for (int r = 0; r < 4; ++r){
            float v = (acc[s][mt][r] + bv) * 0.17677669529663687f;
            int row = mt*16 + g*4 + r;
            qs[row*128 + (((nt*2 + (c>>3)) ^ (row&7))<<3) + c7] = f2bf(v);
          }
      } else if (nt < 12){                       // K
        int ntk = nt - 6;
        #pragma unroll
        for (int mt = 0; mt < 4; ++mt)
          #pragma unroll
          for (int r = 0; r < 4; ++r){
            float v = acc[s][mt][r] + bv;
            int row = mt*16 + g*4 + r;
            ks[row*128 + (((ntk*2 + (c>>3)) ^ (row&7))<<3) + c7] = f2bf(v);
          }
      } else {                                   // V^T: [d][kv], b64 writes
        int d = (nt - 12)*16 + c;
        #pragma unroll
        for (int mt = 0; mt < 4; ++mt){
          short4_t p;
          #pragma unroll
          for (int r = 0; r < 4; ++r) p[r] = (short)f2bf(acc[s][mt][r] + bv);
          int addr = d*64 + (((mt*2 + (g>>1)) ^ c7)<<3) + ((g&1)<<2);
          *(short4_t*)(vT + addr) = p;
        }
      }
    }
  }
  __syncthreads();

  // ---- stage 2: attention; wave w owns m-tile w (16 q tokens), loops 3 heads ----
  unsigned short* pscr = qs + w*2048;            // [16][128] (q slice, per-wave)
  unsigned short* oscr = xs + w*2048;            // [16][128] (xs slice, per-wave)
  {
    short8 qf[3];
    #pragma unroll
    for (int h = 0; h < 3; ++h){
      int row = w*16 + c;
      qf[h] = *(const short8*)(qs + row*128 + (((h*4+g) ^ c7)<<3));
    }
    #pragma unroll
    for (int h = 0; h < 3; ++h){
      short8 kb[4];
      #pragma unroll
      for (int nt = 0; nt < 4; ++nt){
        int row = nt*16 + c;
        kb[nt] = *(const short8*)(ks + row*128 + (((h*4+g) ^ c7)<<3));
      }
      f32x4 sv[4];
      #pragma unroll
      for (int nt = 0; nt < 4; ++nt){
        f32x4 z = {0.f,0.f,0.f,0.f};
        f32x4 a = MFMA(qf[h], kb[nt], z);
        f32x4 bias = *(const f32x4*)(biasf + (((h*4 + w)*4 + nt)*64 + lane)*4);
        sv[nt] = a + bias;
      }
      // softmax over 64 kv (4 in-lane tiles x 16 c-lanes)
      f32x4 mx = vmax4(vmax4(sv[0],sv[1]), vmax4(sv[2],sv[3]));
      #pragma unroll
      for (int off = 1; off <= 8; off <<= 1){
        #pragma unroll
        for (int i2 = 0; i2 < 4; ++i2) mx[i2] = fmaxf(mx[i2], __shfl_xor(mx[i2], off));
      }
      #pragma unroll
      for (int nt = 0; nt < 4; ++nt)
        #pragma unroll
        for (int r = 0; r < 4; ++r)
          sv[nt][r] = exp2f((sv[nt][r] - mx[r]) * 1.4426950408889634f);
      f32x4 sm = sv[0] + sv[1] + sv[2] + sv[3];
      #pragma unroll
      for (int off = 1; off <= 8; off <<= 1){
        #pragma unroll
        for (int i2 = 0; i2 < 4; ++i2) sm[i2] += __shfl_xor(sm[i2], off);
      }
      f32x4 rs;
      #pragma unroll
      for (int r = 0; r < 4; ++r) rs[r] = __builtin_amdgcn_rcpf(sm[r]);
      // P -> per-wave scratch (transpose round-trip)
      #pragma unroll
      for (int nt = 0; nt < 4; ++nt)
        #pragma unroll
        for (int r = 0; r < 4; ++r){
          int lr = g*4 + r;
          pscr[lr*128 + (((nt*2 + (c>>3)) ^ (lr&7))<<3) + c7] = f2bf(sv[nt][r]);
        }
      short8 pf[2];
      #pragma unroll
      for (int ksub = 0; ksub < 2; ++ksub)
        pf[ksub] = *(const short8*)(pscr + c*128 + (((ksub*4+g) ^ c7)<<3));
      // O = (P @ V) * 1/rowsum, via V^T b128 reads
      #pragma unroll
      for (int u = 0; u < 2; ++u){
        int d = h*32 + u*16 + c;
        short8 vb0 = *(const short8*)(vT + d*64 + (((0*4+g) ^ c7)<<3));
        short8 vb1 = *(const short8*)(vT + d*64 + (((1*4+g) ^ c7)<<3));
        f32x4 o = {0.f,0.f,0.f,0.f};
        o = MFMA(pf[0], vb0, o);
        o = MFMA(pf[1], vb1, o);
        #pragma unroll
        for (int r = 0; r < 4; ++r){
          int lr = g*4 + r;
          int col8 = h*4 + u*2 + (c>>3);
          oscr[lr*128 + ((col8 ^ (lr&7))<<3) + c7] = f2bf(o[r] * rs[r]);
        }
      }
    }
  }

  // ---- stage 3: out = O @ Wproj + b (per-wave, no barrier needed) ----
  {
    f32x4 pacc[6];
    #pragma unroll
    for (int nt2 = 0; nt2 < 6; ++nt2){ f32x4 z = {0.f,0.f,0.f,0.f}; pacc[nt2] = z; }
    #pragma unroll
    for (int kt = 0; kt < 3; ++kt){
      short8 afr = *(const short8*)(oscr + c*128 + (((kt*4+g) ^ c7)<<3));
      #pragma unroll
      for (int nt2 = 0; nt2 < 6; ++nt2){
        short8 bfr = *(const short8*)(wp + ((kt*6 + nt2)*64 + lane)*8);
        pacc[nt2] = MFMA(afr, bfr, pacc[nt2]);
      }
    }
    int rowb = w*16 + g*4;
    #pragma unroll
    for (int nt2 = 0; nt2 < 6; ++nt2){
      int n = nt2*16 + c;
      float pb = proj_b[n];
      #pragma unroll
      for (int r = 0; r < 4; ++r){
        int row = rowb + r;
        if (row < 49)
          out[((size_t)b*49 + row)*96 + n] = pacc[nt2][r] + pb;
      }
    }
  }
}

extern "C" void kernel_launch(void* const* d_in, const int* in_sizes, int n_in,
                              void* d_out, int out_size, void* d_ws, size_t ws_size,
                              hipStream_t stream){
  const float* x          = (const float*)d_in[0];
  // d_in[1] = q_global (unused by forward)
  const float* qkv_w      = (const float*)d_in[2];
  const float* qkv_b      = (const float*)d_in[3];
  const float* proj_w     = (const float*)d_in[4];
  const float* proj_b     = (const float*)d_in[5];
  const float* bias_table = (const float*)d_in[6];
  const int*   rel_index  = (const int*)d_in[7];
  float* out = (float*)d_out;
  const int nwin = in_sizes[0] / 4704;   // 49*96

  prep_kernel<<<192, 256, 0, stream>>>(qkv_w, proj_w, bias_table, rel_index,
                                       (unsigned short*)d_ws);

  hipFuncSetAttribute(reinterpret_cast<const void*>(wattn_kernel),
                      hipFuncAttributeMaxDynamicSharedMemorySize, 61440);
  wattn_kernel<<<nwin, 256, 61440, stream>>>(x, qkv_b, proj_b,
                                             (const unsigned short*)d_ws, out);
}